// Round 3
// baseline (90.647 us; speedup 1.0000x reference)
//
#include <hip/hip_runtime.h>
#include <stdint.h>

// GCMConv on MI355X. Data model (verified by rounds 0-2 forensics):
//   x      : float32 (1,16384,8,3,3,2)  — complex pair = float2
//   weight : float32 (4,9,33)
//   out    : float32 (1,16384,8,3,3,2)  — complex pair = float2
//
// Refactor: out[u] = sum_{w16<16} ( N1 @ t[w16] + N2 @ t[w16]^+ ) + N(w=32)
//   where Nk = sum_v weight[u,v,wk] * w_full[v], w_full = [w0..3, w0..3^+, I].
// w matrices live in registers (dagger = free index transpose); LDS holds only
// the 16 transported t matrices per site.

#define SPB 32            // sites per block
#define TPB 128           // 4 threads per site
#define NSITES 16384
#define TS_SITE 292       // 16*18 floats + 4 pad (stride%32==4 -> 2-way max aliasing, free)
#define TS_W 18

__device__ __forceinline__ int neigh(int s, int a){
    // dims (8,8,16,16): d3 bits[0:4), d2 bits[4:8), d1 bits[8:11), d0 bits[11:14)
    if (a == 3) return (s & ~15)        | ((s + 1)    & 15);
    if (a == 2) return (s & ~(15 << 4)) | ((s + 16)   & (15 << 4));
    if (a == 1) return (s & ~(7 << 8))  | ((s + 256)  & (7 << 8));
    return              (s & ~(7 << 11))| ((s + 2048) & (7 << 11));
}

__global__ __launch_bounds__(TPB, 2)
void gcm_fused(const float* __restrict__ xp,
               const float* __restrict__ wgt,
               float* __restrict__ outp)
{
    __shared__ float lt[SPB * TS_SITE];
    const float2* x2 = (const float2*)xp;   // one complex entry
    float2* o2 = (float2*)outp;             // one complex entry

    const int tid = threadIdx.x;
    const int sl  = tid >> 2;
    const int q   = tid & 3;            // phase1: axis; phase2: output channel
    const int s   = blockIdx.x * SPB + sl;

    // ================= phase 1: t[q*4+i] = U_q(s) W_i(s+q^) U_q(s)^+ ==========
    float ure[9], uim[9];
    {
        const float2* up = x2 + (s * 8 + q) * 9;
        #pragma unroll
        for (int e = 0; e < 9; e++){ float2 d = up[e]; ure[e] = d.x; uim[e] = d.y; }
    }
    const int sn = neigh(s, q);
    #pragma unroll
    for (int i = 0; i < 4; i++){
        float wre[9], wim[9];
        {
            const float2* wp = x2 + (sn * 8 + 4 + i) * 9;
            #pragma unroll
            for (int e = 0; e < 9; e++){ float2 d = wp[e]; wre[e] = d.x; wim[e] = d.y; }
        }
        // T1 = U * W
        float t1re[9], t1im[9];
        #pragma unroll
        for (int r = 0; r < 3; r++){
            #pragma unroll
            for (int k = 0; k < 3; k++){
                float ar = 0.f, ai = 0.f;
                #pragma unroll
                for (int j = 0; j < 3; j++){
                    float a_r = ure[r*3+j], a_i = uim[r*3+j];
                    float b_r = wre[j*3+k], b_i = wim[j*3+k];
                    ar = fmaf(a_r, b_r, ar); ar = fmaf(-a_i, b_i, ar);
                    ai = fmaf(a_r, b_i, ai); ai = fmaf(a_i, b_r, ai);
                }
                t1re[r*3+k] = ar; t1im[r*3+k] = ai;
            }
        }
        // T = T1 * U^+ : T[r,k] = sum_j T1[r,j] * conj(U[k,j])
        float* dst = &lt[sl * TS_SITE + (q * 4 + i) * TS_W];
        #pragma unroll
        for (int r = 0; r < 3; r++){
            #pragma unroll
            for (int k = 0; k < 3; k++){
                float ar = 0.f, ai = 0.f;
                #pragma unroll
                for (int j = 0; j < 3; j++){
                    float a_r = t1re[r*3+j], a_i = t1im[r*3+j];
                    float b_r = ure[k*3+j], b_i = uim[k*3+j];
                    ar = fmaf(a_r, b_r, ar); ar = fmaf(a_i, b_i, ar);
                    ai = fmaf(a_i, b_r, ai); ai = fmaf(-a_r, b_i, ai);
                }
                dst[(r*3+k)*2]     = ar;
                dst[(r*3+k)*2 + 1] = ai;
            }
        }
    }
    __syncthreads();

    // ================= phase 2: out channel 4+q for site s =====================
    // pass-through copy of u channel q (exact fp32 copy)
    {
        const float2* src = x2 + (s * 8 + q) * 9;
        float2* dst = o2 + (s * 8 + q) * 9;
        #pragma unroll
        for (int e = 0; e < 9; e++) dst[e] = src[e];
    }
    // own-site w matrices -> registers
    float wr[4][9], wi[4][9];
    #pragma unroll
    for (int v = 0; v < 4; v++){
        const float2* wp = x2 + (s * 8 + 4 + v) * 9;
        #pragma unroll
        for (int e = 0; e < 9; e++){ float2 d = wp[e]; wr[v][e] = d.x; wi[v][e] = d.y; }
    }
    float cre[9], cim[9];
    #pragma unroll
    for (int e = 0; e < 9; e++){ cre[e] = 0.f; cim[e] = 0.f; }

    const float* wq = wgt + q * 9 * 33;   // weight[u=q][v][w]

    // w == 32 term: t_full[32] = I -> out += N(c32)
    {
        float cv[9];
        #pragma unroll
        for (int v = 0; v < 9; v++) cv[v] = wq[v * 33 + 32];
        #pragma unroll
        for (int i = 0; i < 3; i++){
            #pragma unroll
            for (int j = 0; j < 3; j++){
                const int e = i*3+j, eT = j*3+i;
                float nr = (i == j) ? cv[8] : 0.f;
                float ni = 0.f;
                #pragma unroll
                for (int v = 0; v < 4; v++){
                    nr = fmaf(cv[v],    wr[v][e],  nr);
                    nr = fmaf(cv[4+v],  wr[v][eT], nr);
                    ni = fmaf(cv[v],    wi[v][e],  ni);
                    ni = fmaf(-cv[4+v], wi[v][eT], ni);
                }
                cre[e] += nr; cim[e] += ni;
            }
        }
    }

    const float* tbase = &lt[sl * TS_SITE];
    #pragma unroll 2
    for (int w16 = 0; w16 < 16; w16++){
        float tre[9], tim[9];
        {
            const float* tp = tbase + w16 * TS_W;
            #pragma unroll
            for (int e = 0; e < 9; e++){ tre[e] = tp[2*e]; tim[e] = tp[2*e+1]; }
        }
        float nre[9], nim[9];

        // ---- N1 = sum_v weight[q,v,w16] * w_full[v];  out += N1 @ T
        {
            float cv[9];
            #pragma unroll
            for (int v = 0; v < 9; v++) cv[v] = wq[v * 33 + w16];
            #pragma unroll
            for (int i = 0; i < 3; i++){
                #pragma unroll
                for (int j = 0; j < 3; j++){
                    const int e = i*3+j, eT = j*3+i;
                    float nr = (i == j) ? cv[8] : 0.f;
                    float ni = 0.f;
                    #pragma unroll
                    for (int v = 0; v < 4; v++){
                        nr = fmaf(cv[v],    wr[v][e],  nr);
                        nr = fmaf(cv[4+v],  wr[v][eT], nr);
                        ni = fmaf(cv[v],    wi[v][e],  ni);
                        ni = fmaf(-cv[4+v], wi[v][eT], ni);
                    }
                    nre[e] = nr; nim[e] = ni;
                }
            }
        }
        #pragma unroll
        for (int i = 0; i < 3; i++){
            #pragma unroll
            for (int k = 0; k < 3; k++){
                float ar = cre[i*3+k], ai = cim[i*3+k];
                #pragma unroll
                for (int j = 0; j < 3; j++){
                    float n_r = nre[i*3+j], n_i = nim[i*3+j];
                    float b_r = tre[j*3+k], b_i = tim[j*3+k];
                    ar = fmaf(n_r, b_r, ar); ar = fmaf(-n_i, b_i, ar);
                    ai = fmaf(n_r, b_i, ai); ai = fmaf(n_i, b_r, ai);
                }
                cre[i*3+k] = ar; cim[i*3+k] = ai;
            }
        }

        // ---- N2 = sum_v weight[q,v,w16+16] * w_full[v];  out += N2 @ T^+
        {
            float cv[9];
            #pragma unroll
            for (int v = 0; v < 9; v++) cv[v] = wq[v * 33 + 16 + w16];
            #pragma unroll
            for (int i = 0; i < 3; i++){
                #pragma unroll
                for (int j = 0; j < 3; j++){
                    const int e = i*3+j, eT = j*3+i;
                    float nr = (i == j) ? cv[8] : 0.f;
                    float ni = 0.f;
                    #pragma unroll
                    for (int v = 0; v < 4; v++){
                        nr = fmaf(cv[v],    wr[v][e],  nr);
                        nr = fmaf(cv[4+v],  wr[v][eT], nr);
                        ni = fmaf(cv[v],    wi[v][e],  ni);
                        ni = fmaf(-cv[4+v], wi[v][eT], ni);
                    }
                    nre[e] = nr; nim[e] = ni;
                }
            }
        }
        #pragma unroll
        for (int i = 0; i < 3; i++){
            #pragma unroll
            for (int k = 0; k < 3; k++){
                float ar = cre[i*3+k], ai = cim[i*3+k];
                #pragma unroll
                for (int j = 0; j < 3; j++){
                    float n_r = nre[i*3+j], n_i = nim[i*3+j];
                    // T^+[j,k] = ( tre[k*3+j], -tim[k*3+j] )
                    float b_r = tre[k*3+j], b_i = tim[k*3+j];
                    ar = fmaf(n_r, b_r, ar); ar = fmaf(n_i, b_i, ar);
                    ai = fmaf(-n_r, b_i, ai); ai = fmaf(n_i, b_r, ai);
                }
                cre[i*3+k] = ar; cim[i*3+k] = ai;
            }
        }
    }

    // store computed channel 4+q
    {
        float2* dst = o2 + (s * 8 + 4 + q) * 9;
        #pragma unroll
        for (int e = 0; e < 9; e++){ float2 d; d.x = cre[e]; d.y = cim[e]; dst[e] = d; }
    }
}

extern "C" void kernel_launch(void* const* d_in, const int* in_sizes, int n_in,
                              void* d_out, int out_size, void* d_ws, size_t ws_size,
                              hipStream_t stream)
{
    const float* x = (const float*)d_in[0];
    const float* w = (const float*)d_in[1];
    float* out = (float*)d_out;
    dim3 grid(NSITES / SPB);
    dim3 block(TPB);
    hipLaunchKernelGGL(gcm_fused, grid, block, 0, stream, x, w, out);
}